// Round 2
// baseline (293.209 us; speedup 1.0000x reference)
//
#include <hip/hip_runtime.h>
#include <math.h>

#define DT 0.1f

typedef __attribute__((ext_vector_type(4)))  short short4v;
typedef __attribute__((ext_vector_type(8)))  short short8;
typedef __attribute__((ext_vector_type(16))) float f32x16;

__device__ __forceinline__ short f2bf(float x) {
    unsigned int u = __float_as_uint(x);
    unsigned int r = (u + 0x7fffu + ((u >> 16) & 1u)) >> 16;  // RNE
    return (short)r;
}
__device__ __forceinline__ float bf2f(short s) {
    return __uint_as_float(((unsigned int)(unsigned short)s) << 16);
}
__device__ __forceinline__ float tanh_fast(float x) {
    float e = __expf(x + x);
    float r = __builtin_amdgcn_rcpf(e + 1.f);
    return __builtin_fmaf(-2.f, r, 1.f);
}

// ---------------- weight packing: 32x32x16 MFMA B-fragment order -----------
// lane holds B[k = kt*16 + (lane>>5)*8 + j][n = nt*32 + (lane&31)]
// at out[((nt*KT + kt)*64 + lane)*8 + j],  KT = K/16   (verified R5)
__device__ __forceinline__ void pack32_body(const float* __restrict__ W,
                                            short* __restrict__ out,
                                            int K, int N, int idx, bool trans)
{
    int j = idx & 7, lane = (idx >> 3) & 63, rest = idx >> 9;
    int KT = K >> 4;
    int kt = rest % KT, nt = rest / KT;
    int k = kt * 16 + (lane >> 5) * 8 + j;
    int n = nt * 32 + (lane & 31);
    out[idx] = f2bf(trans ? W[n * K + k] : W[k * N + n]);
}

// One launch for ALL preprocessing (same block map as R1).
__global__ __launch_bounds__(256)
void prep(const float* __restrict__ W1, const float* __restrict__ W2,
          const float* __restrict__ z,
          short* __restrict__ PBSq, short* __restrict__ PBSp,
          short* __restrict__ PB2, short* __restrict__ PB2T,
          short* __restrict__ PB1q, short* __restrict__ PB1Tp,
          short* __restrict__ zpA)
{
    __shared__ short zb[32 * 520];
    const int tid = threadIdx.x;
    const int b = blockIdx.x;

    if (b < 512) {
        // S_qp = -0.5*dt * W1^T[:, :512] @ W1[512:, :]   (b <  256, k = b)
        // S_pq =      dt * W1^T[:, 512:] @ W1[:512, :]   (b >= 256, k = b-256)
        const int n = tid;
        float s[8];
#pragma unroll
        for (int i = 0; i < 8; ++i) s[i] = 0.f;
        int k; float coef; short* dst;
        if (b < 256) {
            k = b; coef = -0.5f * DT; dst = PBSq;
            for (int c = 0; c < 512; c += 8) {
#pragma unroll
                for (int i = 0; i < 8; ++i)
                    s[i] = __builtin_fmaf(W1[(c + i) * 256 + k],
                                          W1[(512 + c + i) * 256 + n], s[i]);
            }
        } else {
            k = b - 256; coef = DT; dst = PBSp;
            for (int c = 0; c < 512; c += 8) {
#pragma unroll
                for (int i = 0; i < 8; ++i)
                    s[i] = __builtin_fmaf(W1[(512 + c + i) * 256 + k],
                                          W1[(c + i) * 256 + n], s[i]);
            }
        }
        float v = coef * (((s[0] + s[1]) + (s[2] + s[3])) +
                          ((s[4] + s[5]) + (s[6] + s[7])));
        // write directly at packed B-frag position (inverse of pack32_direct)
        int kt = k >> 4, r = k & 15;
        int lane = (r >> 3) * 32 + (n & 31), nt = n >> 5;
        dst[(((nt * 16 + kt) * 64 + lane) << 3) + (r & 7)] = f2bf(v);
    } else if (b < 768) {
        pack32_body(W2, PB2, 256, 256, (b - 512) * 256 + tid, false);
    } else if (b < 1024) {
        pack32_body(W2, PB2T, 256, 256, (b - 768) * 256 + tid, true);
    } else if (b < 1536) {
        pack32_body(W1, PB1q, 512, 256, (b - 1024) * 256 + tid, false);
    } else if (b < 2048) {
        pack32_body(W1 + 512 * 256, PB1Tp, 256, 512, (b - 1536) * 256 + tid, true);
    } else {
        // z (16384x512 fp32) -> A-frag-packed bf16, coalesced via LDS staging.
        const int bx = b - 2048;               // 512 blocks x 32 rows
#pragma unroll
        for (int j = 0; j < 16; ++j) {
            int lin = j * 256 + tid;           // 4096 float4
            int r = lin >> 7, c4 = lin & 127;
            float4 v = ((const float4*)z)[(size_t)(bx * 32 + r) * 128 + c4];
            short4v pk;
            pk.x = f2bf(v.x); pk.y = f2bf(v.y); pk.z = f2bf(v.z); pk.w = f2bf(v.w);
            *(short4v*)&zb[r * 520 + c4 * 4] = pk;
        }
        __syncthreads();
        const int lane = tid & 63, w = tid >> 6;
        const int m = lane & 31, lh = lane >> 5;
#pragma unroll
        for (int j = 0; j < 8; ++j) {
            int kt = w * 8 + j;
            short8 f = *(const short8*)&zb[m * 520 + kt * 16 + lh * 8];
            *(short8*)(zpA + (((size_t)bx * 32 + kt) * 64 + lane) * 8) = f;
        }
    }
}

// ---------------- LDS tile layout, 32-row block version --------------------
// tile nt: 64 slots x 16 shorts; rot = ((l31>>2)&3)*4  (same swizzle as R1)
__device__ __forceinline__ short8 lds_frag32(const short* Ac, int kt,
                                             int l31, int lh, int rot)
{
    int nt_s = kt >> 1;
    int po = (((kt & 1) * 2 + lh) * 4 + rot) & 15;
    int base = (nt_s * 64 + l31) * 16 + po;
    short4v x = *(const short4v*)&Ac[base];
    short4v y = *(const short4v*)&Ac[base + 512];   // slot l31+32, same tile
    short8 r;
    r[0] = x.x; r[1] = x.y; r[2] = x.z; r[3] = x.w;
    r[4] = y.x; r[5] = y.y; r[6] = y.z; r[7] = y.w;
    return r;
}
__device__ __forceinline__ void store_tile32(short* Ac, int nt, int lane,
                                             int rot, const f32x16 v)
{
    int base = (nt * 64 + lane) * 16;
#pragma unroll
    for (int c = 0; c < 4; ++c) {
        short4v pk;
        pk.x = f2bf(v[4 * c + 0]); pk.y = f2bf(v[4 * c + 1]);
        pk.z = f2bf(v[4 * c + 2]); pk.w = f2bf(v[4 * c + 3]);
        *(short4v*)&Ac[base + ((4 * c + rot) & 15)] = pk;
    }
}

// K=256 gemm, single 32x32 output tile per wave.
// B prefetch depth 8 (global/L2), A prefetch depth 2 (LDS).
__device__ __forceinline__ void gemm_nt32(const short* Ac, int l31, int lh, int rot,
                                          const short8* __restrict__ Bf, f32x16& acc)
{
    short8 pb[8];
#pragma unroll
    for (int k = 0; k < 8; ++k) pb[k] = Bf[k * 64];
    short8 pa0 = lds_frag32(Ac, 0, l31, lh, rot);
    short8 pa1 = lds_frag32(Ac, 1, l31, lh, rot);
#pragma unroll
    for (int kt = 0; kt < 16; ++kt) {
        short8 ca = pa0, cb = pb[kt & 7];
        pa0 = pa1;
        if (kt + 2 < 16) pa1 = lds_frag32(Ac, kt + 2, l31, lh, rot);
        if (kt + 8 < 16) pb[kt & 7] = Bf[(kt + 8) * 64];
        acc = __builtin_amdgcn_mfma_f32_32x32x16_bf16(ca, cb, acc, 0, 0, 0);
    }
}

// ---------------- fused leapfrog: 32 rows/block, 512 blocks, 2 blocks/CU ---
__global__ __launch_bounds__(512, 4)
void mega(const short* __restrict__ zpA,
          const short* __restrict__ PB1q,
          const short* __restrict__ PB2,
          const short* __restrict__ PB2T,
          const short* __restrict__ PBSq,
          const short* __restrict__ PBSp,
          const float* __restrict__ b1,
          const float* __restrict__ b2,
          const float* __restrict__ W3,
          const short* __restrict__ PB1Tp,
          const float* __restrict__ z,
          float* __restrict__ out)
{
    __shared__ alignas(16) short smem[16384];   // 32 KB
    short* h1_c = smem;             // 8 nt x 64 x 16
    short* da_c = smem + 8192;

    const int tid = threadIdx.x;
    const int lane = tid & 63, w = tid >> 6;   // w = nt strip, 0..7
    const int l31 = lane & 31, lh = lane >> 5;
    const int rot = ((l31 >> 2) & 3) * 4;
    const int bx = blockIdx.x;                 // 512 blocks x 32 rows

    const int col = w * 32 + l31;
    const float b1v = b1[col], b2v = b2[col], w3v = W3[col];

    f32x16 A1 = 0.f;
    f32x16 dsum = 0.f;

    // GEMM1: A1 = z @ W1[:512,:]  (K=512, A frags from global, KT=32)
    {
        const short8* Af = (const short8*)zpA + ((size_t)bx * 32) * 64 + lane;
        const short8* Bf = (const short8*)PB1q + ((size_t)w * 32) * 64 + lane;
        short8 pa[4], pb[8];
#pragma unroll
        for (int k = 0; k < 4; ++k) pa[k] = Af[k * 64];
#pragma unroll
        for (int k = 0; k < 8; ++k) pb[k] = Bf[k * 64];
#pragma unroll
        for (int kt = 0; kt < 32; ++kt) {
            short8 ca = pa[kt & 3], cb = pb[kt & 7];
            if (kt + 4 < 32) pa[kt & 3] = Af[(kt + 4) * 64];
            if (kt + 8 < 32) pb[kt & 7] = Bf[(kt + 8) * 64];
            A1 = __builtin_amdgcn_mfma_f32_32x32x16_bf16(ca, cb, A1, 0, 0, 0);
        }
    }

    for (int it = 0; it < 8; ++it) {
        const bool isq = ((it % 3) == 1);

        // P1: h1 = tanh(A1 + b1)
        {
            f32x16 hv;
#pragma unroll
            for (int r = 0; r < 16; ++r) hv[r] = tanh_fast(A1[r] + b1v);
            store_tile32(h1_c, w, lane, rot, hv);
        }
        __syncthreads();

        // P2: da2 = W3*(1-tanh^2(h1@W2 + b2))
        {
            f32x16 t0 = 0.f;
            gemm_nt32(h1_c, l31, lh, rot,
                      (const short8*)PB2 + ((size_t)w * 16) * 64 + lane, t0);
            f32x16 d;
#pragma unroll
            for (int r = 0; r < 16; ++r) {
                float ta = tanh_fast(t0[r] + b2v);
                d[r] = w3v * (1.f - ta * ta);
            }
            store_tile32(da_c, w, lane, rot, d);
        }
        __syncthreads();

        // P3: da1 = (da2@W2^T) * (1-h1^2)
        {
            f32x16 t0 = 0.f;
            gemm_nt32(da_c, l31, lh, rot,
                      (const short8*)PB2T + ((size_t)w * 16) * 64 + lane, t0);
            __syncthreads();   // all waves done reading da2
            f32x16 d;
            const int basei = (w * 64 + lane) * 16;
#pragma unroll
            for (int c = 0; c < 4; ++c) {
                short4v h4 = *(const short4v*)&h1_c[basei + ((4 * c + rot) & 15)];
                float h0 = bf2f(h4.x), h1f = bf2f(h4.y);
                float h2 = bf2f(h4.z), h3 = bf2f(h4.w);
                d[4 * c + 0] = t0[4 * c + 0] * (1.f - h0 * h0);
                d[4 * c + 1] = t0[4 * c + 1] * (1.f - h1f * h1f);
                d[4 * c + 2] = t0[4 * c + 2] * (1.f - h2 * h2);
                d[4 * c + 3] = t0[4 * c + 3] * (1.f - h3 * h3);
            }
            if (isq) dsum += d;
            store_tile32(da_c, w, lane, rot, d);
        }
        __syncthreads();

        // P4: A1 += da1 @ S  (coef folded into S; skip on last eval)
        if (it < 7) {
            const short* S = isq ? PBSp : PBSq;
            gemm_nt32(da_c, l31, lh, rot,
                      (const short8*)S + ((size_t)w * 16) * 64 + lane, A1);
            // safe: every wave's P4 reads complete before it reaches the
            // next-iteration P1 barrier, which precedes any da_c overwrite.
        }
    }

    // ---- fused out-gemm: C = dsum @ W1^T[:,512:], out = z + DT*C ----------
    store_tile32(da_c, w, lane, rot, dsum);
    __syncthreads();

    // wave w -> output col-tiles {2w, 2w+1} (cols [w*64, w*64+64))
    f32x16 acc2[2];
    acc2[0] = 0.f; acc2[1] = 0.f;
    {
        const short8* Bf0 = (const short8*)PB1Tp + (size_t)(2 * w + 0) * 16 * 64 + lane;
        const short8* Bf1 = (const short8*)PB1Tp + (size_t)(2 * w + 1) * 16 * 64 + lane;
        short8 pb0[4], pb1[4];
#pragma unroll
        for (int k = 0; k < 4; ++k) { pb0[k] = Bf0[k * 64]; pb1[k] = Bf1[k * 64]; }
        short8 pa0 = lds_frag32(da_c, 0, l31, lh, rot);
        short8 pa1 = lds_frag32(da_c, 1, l31, lh, rot);
#pragma unroll
        for (int kt = 0; kt < 16; ++kt) {
            short8 ca = pa0, cb0 = pb0[kt & 3], cb1 = pb1[kt & 3];
            pa0 = pa1;
            if (kt + 2 < 16) pa1 = lds_frag32(da_c, kt + 2, l31, lh, rot);
            if (kt + 4 < 16) {
                pb0[kt & 3] = Bf0[(kt + 4) * 64];
                pb1[kt & 3] = Bf1[(kt + 4) * 64];
            }
            acc2[0] = __builtin_amdgcn_mfma_f32_32x32x16_bf16(ca, cb0, acc2[0], 0, 0, 0);
            acc2[1] = __builtin_amdgcn_mfma_f32_32x32x16_bf16(ca, cb1, acc2[1], 0, 0, 0);
        }
    }
    __syncthreads();   // all A-frag reads of da_c done before Ct overwrite

    // coalesced epilogue via LDS fp32 (reuses the 32 KB), two 256-col passes
    float* Ct = (float*)smem;                 // 32 x 256 fp32 = 32 KB
#pragma unroll
    for (int p = 0; p < 2; ++p) {
        if ((w >> 2) == p) {                  // waves owning cols [p*256, p*256+256)
#pragma unroll
            for (int t = 0; t < 2; ++t) {
                const int cl = (w & 3) * 64 + t * 32 + l31;
#pragma unroll
                for (int r = 0; r < 16; ++r) {
                    int row = (r & 3) + 8 * (r >> 2) + 4 * lh;
                    Ct[row * 256 + cl] = acc2[t][r];
                }
            }
        }
        __syncthreads();
#pragma unroll
        for (int j = 0; j < 4; ++j) {
            int lin = j * 512 + tid;          // 2048 float4 per pass
            int r = lin >> 6, c4 = lin & 63;
            size_t gi = (size_t)(bx * 32 + r) * 128 + p * 64 + c4;
            float4 zv = ((const float4*)z)[gi];
            float4 cv = *(const float4*)&Ct[r * 256 + c4 * 4];
            float4 ov;
            ov.x = zv.x + DT * cv.x; ov.y = zv.y + DT * cv.y;
            ov.z = zv.z + DT * cv.z; ov.w = zv.w + DT * cv.w;
            ((float4*)out)[gi] = ov;
        }
        __syncthreads();
    }
}

extern "C" void kernel_launch(void* const* d_in, const int* in_sizes, int n_in,
                              void* d_out, int out_size, void* d_ws, size_t ws_size,
                              hipStream_t stream)
{
    const float* z  = (const float*)d_in[0];
    const float* W1 = (const float*)d_in[1];   // 1024 x 256
    const float* b1 = (const float*)d_in[2];
    const float* W2 = (const float*)d_in[3];   // 256 x 256
    const float* b2 = (const float*)d_in[4];
    const float* W3 = (const float*)d_in[5];   // 256 x 1
    float* out = (float*)d_out;

    short* PB2   = (short*)d_ws;
    short* PB2T  = PB2   + 65536;
    short* PBSq  = PB2T  + 65536;
    short* PBSp  = PBSq  + 65536;
    short* PB1q  = PBSp  + 65536;              // K=512,N=256
    short* PB1Tp = PB1q  + 131072;             // K=256,N=512
    short* zpA   = PB1Tp + 131072;             // 16 MB

    prep<<<2560, 256, 0, stream>>>(W1, W2, z, PBSq, PBSp, PB2, PB2T,
                                   PB1q, PB1Tp, zpA);
    mega<<<512, 512, 0, stream>>>(zpA, PB1q, PB2, PB2T, PBSq, PBSp,
                                  b1, b2, W3, PB1Tp, z, out);
}

// Round 3
// 200.848 us; speedup vs baseline: 1.4599x; 1.4599x over previous
//
#include <hip/hip_runtime.h>
#include <math.h>

#define DT 0.1f

typedef __attribute__((ext_vector_type(4)))  short short4v;
typedef __attribute__((ext_vector_type(8)))  short short8;
typedef __attribute__((ext_vector_type(16))) float f32x16;

__device__ __forceinline__ short f2bf(float x) {
    unsigned int u = __float_as_uint(x);
    unsigned int r = (u + 0x7fffu + ((u >> 16) & 1u)) >> 16;  // RNE
    return (short)r;
}
__device__ __forceinline__ float bf2f(short s) {
    return __uint_as_float(((unsigned int)(unsigned short)s) << 16);
}
__device__ __forceinline__ float tanh_fast(float x) {
    float e = __expf(x + x);
    float r = __builtin_amdgcn_rcpf(e + 1.f);
    return __builtin_fmaf(-2.f, r, 1.f);
}

// ---------------- weight packing: 32x32x16 MFMA B-fragment order -----------
// lane holds B[k = kt*16 + (lane>>5)*8 + j][n = nt*32 + (lane&31)]
// at out[((nt*KT + kt)*64 + lane)*8 + j],  KT = K/16   (verified R5)
__device__ __forceinline__ void pack32_body(const float* __restrict__ W,
                                            short* __restrict__ out,
                                            int K, int N, int idx, bool trans)
{
    int j = idx & 7, lane = (idx >> 3) & 63, rest = idx >> 9;
    int KT = K >> 4;
    int kt = rest % KT, nt = rest / KT;
    int k = kt * 16 + (lane >> 5) * 8 + j;
    int n = nt * 32 + (lane & 31);
    out[idx] = f2bf(trans ? W[n * K + k] : W[k * N + n]);
}

// One launch for ALL preprocessing (same block map as R1).
__global__ __launch_bounds__(256)
void prep(const float* __restrict__ W1, const float* __restrict__ W2,
          const float* __restrict__ z,
          short* __restrict__ PBSq, short* __restrict__ PBSp,
          short* __restrict__ PB2, short* __restrict__ PB2T,
          short* __restrict__ PB1q, short* __restrict__ PB1Tp,
          short* __restrict__ zpA)
{
    __shared__ short zb[32 * 520];
    const int tid = threadIdx.x;
    const int b = blockIdx.x;

    if (b < 512) {
        // S_qp = -0.5*dt * W1^T[:, :512] @ W1[512:, :]   (b <  256, k = b)
        // S_pq =      dt * W1^T[:, 512:] @ W1[:512, :]   (b >= 256, k = b-256)
        const int n = tid;
        float s[8];
#pragma unroll
        for (int i = 0; i < 8; ++i) s[i] = 0.f;
        int k; float coef; short* dst;
        if (b < 256) {
            k = b; coef = -0.5f * DT; dst = PBSq;
            for (int c = 0; c < 512; c += 8) {
#pragma unroll
                for (int i = 0; i < 8; ++i)
                    s[i] = __builtin_fmaf(W1[(c + i) * 256 + k],
                                          W1[(512 + c + i) * 256 + n], s[i]);
            }
        } else {
            k = b - 256; coef = DT; dst = PBSp;
            for (int c = 0; c < 512; c += 8) {
#pragma unroll
                for (int i = 0; i < 8; ++i)
                    s[i] = __builtin_fmaf(W1[(512 + c + i) * 256 + k],
                                          W1[(c + i) * 256 + n], s[i]);
            }
        }
        float v = coef * (((s[0] + s[1]) + (s[2] + s[3])) +
                          ((s[4] + s[5]) + (s[6] + s[7])));
        // write directly at packed B-frag position (inverse of pack32_direct)
        int kt = k >> 4, r = k & 15;
        int lane = (r >> 3) * 32 + (n & 31), nt = n >> 5;
        dst[(((nt * 16 + kt) * 64 + lane) << 3) + (r & 7)] = f2bf(v);
    } else if (b < 768) {
        pack32_body(W2, PB2, 256, 256, (b - 512) * 256 + tid, false);
    } else if (b < 1024) {
        pack32_body(W2, PB2T, 256, 256, (b - 768) * 256 + tid, true);
    } else if (b < 1536) {
        pack32_body(W1, PB1q, 512, 256, (b - 1024) * 256 + tid, false);
    } else if (b < 2048) {
        pack32_body(W1 + 512 * 256, PB1Tp, 256, 512, (b - 1536) * 256 + tid, true);
    } else {
        // z (16384x512 fp32) -> A-frag-packed bf16, coalesced via LDS staging.
        const int bx = b - 2048;               // 512 blocks x 32 rows
#pragma unroll
        for (int j = 0; j < 16; ++j) {
            int lin = j * 256 + tid;           // 4096 float4
            int r = lin >> 7, c4 = lin & 127;
            float4 v = ((const float4*)z)[(size_t)(bx * 32 + r) * 128 + c4];
            short4v pk;
            pk.x = f2bf(v.x); pk.y = f2bf(v.y); pk.z = f2bf(v.z); pk.w = f2bf(v.w);
            *(short4v*)&zb[r * 520 + c4 * 4] = pk;
        }
        __syncthreads();
        const int lane = tid & 63, w = tid >> 6;
        const int m = lane & 31, lh = lane >> 5;
#pragma unroll
        for (int j = 0; j < 8; ++j) {
            int kt = w * 8 + j;
            short8 f = *(const short8*)&zb[m * 520 + kt * 16 + lh * 8];
            *(short8*)(zpA + (((size_t)bx * 32 + kt) * 64 + lane) * 8) = f;
        }
    }
}

// ---------------- LDS tile layout, 32-row block version --------------------
// tile nt: 64 slots x 16 shorts; rot = ((l31>>2)&3)*4  (same swizzle as R1)
__device__ __forceinline__ short8 lds_frag32(const short* Ac, int kt,
                                             int l31, int lh, int rot)
{
    int nt_s = kt >> 1;
    int po = (((kt & 1) * 2 + lh) * 4 + rot) & 15;
    int base = (nt_s * 64 + l31) * 16 + po;
    short4v x = *(const short4v*)&Ac[base];
    short4v y = *(const short4v*)&Ac[base + 512];   // slot l31+32, same tile
    short8 r;
    r[0] = x.x; r[1] = x.y; r[2] = x.z; r[3] = x.w;
    r[4] = y.x; r[5] = y.y; r[6] = y.z; r[7] = y.w;
    return r;
}
__device__ __forceinline__ void store_tile32(short* Ac, int nt, int lane,
                                             int rot, const f32x16 v)
{
    int base = (nt * 64 + lane) * 16;
#pragma unroll
    for (int c = 0; c < 4; ++c) {
        short4v pk;
        pk.x = f2bf(v[4 * c + 0]); pk.y = f2bf(v[4 * c + 1]);
        pk.z = f2bf(v[4 * c + 2]); pk.w = f2bf(v[4 * c + 3]);
        *(short4v*)&Ac[base + ((4 * c + rot) & 15)] = pk;
    }
}

// K=256 gemm, single 32x32 output tile per wave.
// B prefetch depth 8 (global/L2), A prefetch depth 2 (LDS).
__device__ __forceinline__ void gemm_nt32(const short* Ac, int l31, int lh, int rot,
                                          const short8* __restrict__ Bf, f32x16& acc)
{
    short8 pb[8];
#pragma unroll
    for (int k = 0; k < 8; ++k) pb[k] = Bf[k * 64];
    short8 pa0 = lds_frag32(Ac, 0, l31, lh, rot);
    short8 pa1 = lds_frag32(Ac, 1, l31, lh, rot);
#pragma unroll
    for (int kt = 0; kt < 16; ++kt) {
        short8 ca = pa0, cb = pb[kt & 7];
        pa0 = pa1;
        if (kt + 2 < 16) pa1 = lds_frag32(Ac, kt + 2, l31, lh, rot);
        if (kt + 8 < 16) pb[kt & 7] = Bf[(kt + 8) * 64];
        acc = __builtin_amdgcn_mfma_f32_32x32x16_bf16(ca, cb, acc, 0, 0, 0);
    }
}

// ---------------- fused leapfrog: 32 rows/block, 512 blocks ----------------
// __launch_bounds__(512, 2): this toolchain treats arg2 as BLOCKS/CU —
// (512,4) forced a 64-VGPR cap and massive scratch spills (R2: FETCH 29->498MB).
// (512,2) -> 128 VGPR cap = 4 waves/SIMD = the 2 blocks/CU we want, no spill.
__global__ __launch_bounds__(512, 2)
void mega(const short* __restrict__ zpA,
          const short* __restrict__ PB1q,
          const short* __restrict__ PB2,
          const short* __restrict__ PB2T,
          const short* __restrict__ PBSq,
          const short* __restrict__ PBSp,
          const float* __restrict__ b1,
          const float* __restrict__ b2,
          const float* __restrict__ W3,
          const short* __restrict__ PB1Tp,
          const float* __restrict__ z,
          float* __restrict__ out)
{
    __shared__ alignas(16) short smem[16384];   // 32 KB
    short* h1_c = smem;             // 8 nt x 64 x 16
    short* da_c = smem + 8192;

    const int tid = threadIdx.x;
    const int lane = tid & 63, w = tid >> 6;   // w = nt strip, 0..7
    const int l31 = lane & 31, lh = lane >> 5;
    const int rot = ((l31 >> 2) & 3) * 4;
    const int bx = blockIdx.x;                 // 512 blocks x 32 rows

    const int col = w * 32 + l31;
    const float b1v = b1[col], b2v = b2[col], w3v = W3[col];

    f32x16 A1 = 0.f;
    f32x16 dsum = 0.f;

    // GEMM1: A1 = z @ W1[:512,:]  (K=512, A frags from global, KT=32)
    {
        const short8* Af = (const short8*)zpA + ((size_t)bx * 32) * 64 + lane;
        const short8* Bf = (const short8*)PB1q + ((size_t)w * 32) * 64 + lane;
        short8 pa[4], pb[8];
#pragma unroll
        for (int k = 0; k < 4; ++k) pa[k] = Af[k * 64];
#pragma unroll
        for (int k = 0; k < 8; ++k) pb[k] = Bf[k * 64];
#pragma unroll
        for (int kt = 0; kt < 32; ++kt) {
            short8 ca = pa[kt & 3], cb = pb[kt & 7];
            if (kt + 4 < 32) pa[kt & 3] = Af[(kt + 4) * 64];
            if (kt + 8 < 32) pb[kt & 7] = Bf[(kt + 8) * 64];
            A1 = __builtin_amdgcn_mfma_f32_32x32x16_bf16(ca, cb, A1, 0, 0, 0);
        }
    }

    for (int it = 0; it < 8; ++it) {
        const bool isq = ((it % 3) == 1);

        // P1: h1 = tanh(A1 + b1)
        {
            f32x16 hv;
#pragma unroll
            for (int r = 0; r < 16; ++r) hv[r] = tanh_fast(A1[r] + b1v);
            store_tile32(h1_c, w, lane, rot, hv);
        }
        __syncthreads();

        // P2: da2 = W3*(1-tanh^2(h1@W2 + b2))
        {
            f32x16 t0 = 0.f;
            gemm_nt32(h1_c, l31, lh, rot,
                      (const short8*)PB2 + ((size_t)w * 16) * 64 + lane, t0);
            f32x16 d;
#pragma unroll
            for (int r = 0; r < 16; ++r) {
                float ta = tanh_fast(t0[r] + b2v);
                d[r] = w3v * (1.f - ta * ta);
            }
            store_tile32(da_c, w, lane, rot, d);
        }
        __syncthreads();

        // P3: da1 = (da2@W2^T) * (1-h1^2)
        {
            f32x16 t0 = 0.f;
            gemm_nt32(da_c, l31, lh, rot,
                      (const short8*)PB2T + ((size_t)w * 16) * 64 + lane, t0);
            __syncthreads();   // all waves done reading da2
            f32x16 d;
            const int basei = (w * 64 + lane) * 16;
#pragma unroll
            for (int c = 0; c < 4; ++c) {
                short4v h4 = *(const short4v*)&h1_c[basei + ((4 * c + rot) & 15)];
                float h0 = bf2f(h4.x), h1f = bf2f(h4.y);
                float h2 = bf2f(h4.z), h3 = bf2f(h4.w);
                d[4 * c + 0] = t0[4 * c + 0] * (1.f - h0 * h0);
                d[4 * c + 1] = t0[4 * c + 1] * (1.f - h1f * h1f);
                d[4 * c + 2] = t0[4 * c + 2] * (1.f - h2 * h2);
                d[4 * c + 3] = t0[4 * c + 3] * (1.f - h3 * h3);
            }
            if (isq) dsum += d;
            store_tile32(da_c, w, lane, rot, d);
        }
        __syncthreads();

        // P4: A1 += da1 @ S  (coef folded into S; skip on last eval)
        if (it < 7) {
            const short* S = isq ? PBSp : PBSq;
            gemm_nt32(da_c, l31, lh, rot,
                      (const short8*)S + ((size_t)w * 16) * 64 + lane, A1);
            // safe: every wave's P4 reads complete before it reaches the
            // next-iteration P1 barrier, which precedes any da_c overwrite.
        }
    }

    // ---- fused out-gemm: C = dsum @ W1^T[:,512:], out = z + DT*C ----------
    store_tile32(da_c, w, lane, rot, dsum);
    __syncthreads();

    // wave w -> output col-tiles {2w, 2w+1} (cols [w*64, w*64+64))
    f32x16 acc2[2];
    acc2[0] = 0.f; acc2[1] = 0.f;
    {
        const short8* Bf0 = (const short8*)PB1Tp + (size_t)(2 * w + 0) * 16 * 64 + lane;
        const short8* Bf1 = (const short8*)PB1Tp + (size_t)(2 * w + 1) * 16 * 64 + lane;
        short8 pb0[4], pb1[4];
#pragma unroll
        for (int k = 0; k < 4; ++k) { pb0[k] = Bf0[k * 64]; pb1[k] = Bf1[k * 64]; }
        short8 pa0 = lds_frag32(da_c, 0, l31, lh, rot);
        short8 pa1 = lds_frag32(da_c, 1, l31, lh, rot);
#pragma unroll
        for (int kt = 0; kt < 16; ++kt) {
            short8 ca = pa0, cb0 = pb0[kt & 3], cb1 = pb1[kt & 3];
            pa0 = pa1;
            if (kt + 2 < 16) pa1 = lds_frag32(da_c, kt + 2, l31, lh, rot);
            if (kt + 4 < 16) {
                pb0[kt & 3] = Bf0[(kt + 4) * 64];
                pb1[kt & 3] = Bf1[(kt + 4) * 64];
            }
            acc2[0] = __builtin_amdgcn_mfma_f32_32x32x16_bf16(ca, cb0, acc2[0], 0, 0, 0);
            acc2[1] = __builtin_amdgcn_mfma_f32_32x32x16_bf16(ca, cb1, acc2[1], 0, 0, 0);
        }
    }
    __syncthreads();   // all A-frag reads of da_c done before Ct overwrite

    // coalesced epilogue via LDS fp32 (reuses the 32 KB), two 256-col passes
    float* Ct = (float*)smem;                 // 32 x 256 fp32 = 32 KB
#pragma unroll
    for (int p = 0; p < 2; ++p) {
        if ((w >> 2) == p) {                  // waves owning cols [p*256, p*256+256)
#pragma unroll
            for (int t = 0; t < 2; ++t) {
                const int cl = (w & 3) * 64 + t * 32 + l31;
#pragma unroll
                for (int r = 0; r < 16; ++r) {
                    int row = (r & 3) + 8 * (r >> 2) + 4 * lh;
                    Ct[row * 256 + cl] = acc2[t][r];
                }
            }
        }
        __syncthreads();
#pragma unroll
        for (int j = 0; j < 4; ++j) {
            int lin = j * 512 + tid;          // 2048 float4 per pass
            int r = lin >> 6, c4 = lin & 63;
            size_t gi = (size_t)(bx * 32 + r) * 128 + p * 64 + c4;
            float4 zv = ((const float4*)z)[gi];
            float4 cv = *(const float4*)&Ct[r * 256 + c4 * 4];
            float4 ov;
            ov.x = zv.x + DT * cv.x; ov.y = zv.y + DT * cv.y;
            ov.z = zv.z + DT * cv.z; ov.w = zv.w + DT * cv.w;
            ((float4*)out)[gi] = ov;
        }
        __syncthreads();
    }
}

extern "C" void kernel_launch(void* const* d_in, const int* in_sizes, int n_in,
                              void* d_out, int out_size, void* d_ws, size_t ws_size,
                              hipStream_t stream)
{
    const float* z  = (const float*)d_in[0];
    const float* W1 = (const float*)d_in[1];   // 1024 x 256
    const float* b1 = (const float*)d_in[2];
    const float* W2 = (const float*)d_in[3];   // 256 x 256
    const float* b2 = (const float*)d_in[4];
    const float* W3 = (const float*)d_in[5];   // 256 x 1
    float* out = (float*)d_out;

    short* PB2   = (short*)d_ws;
    short* PB2T  = PB2   + 65536;
    short* PBSq  = PB2T  + 65536;
    short* PBSp  = PBSq  + 65536;
    short* PB1q  = PBSp  + 65536;              // K=512,N=256
    short* PB1Tp = PB1q  + 131072;             // K=256,N=512
    short* zpA   = PB1Tp + 131072;             // 16 MB

    prep<<<2560, 256, 0, stream>>>(W1, W2, z, PBSq, PBSp, PB2, PB2T,
                                   PB1q, PB1Tp, zpA);
    mega<<<512, 512, 0, stream>>>(zpA, PB1q, PB2, PB2T, PBSq, PBSp,
                                  b1, b2, W3, PB1Tp, z, out);
}